// Round 9
// baseline (167.806 us; speedup 1.0000x reference)
//
#include <hip/hip_runtime.h>

namespace {

constexpr int T_STEPS = 1024;
constexpr int BATCH   = 16;
constexpr int NNEUR   = 2048;
constexpr int MCOLS   = 512;
constexpr int BN      = BATCH * NNEUR;   // 32768

constexpr double DT_D   = 1e-7;
constexpr double TAU_D  = 1e-4;

constexpr float DT_F     = 1e-7f;
constexpr float CMEM_F   = 1e-12f;
constexpr float GLEAK_F  = 1e-9f;
constexpr float VTH_F    = 0.7f;             // VTH * GAIN
constexpr float REFRAC_F = 1e-6f;
constexpr float AINC_F   = 5e-11f;
constexpr float DECAY_F  = (float)(1.0 - DT_D / TAU_D);   // 0.999f
constexpr float VRESET_F = 0.0f;

// TLP loader design: 256 blocks x 640 threads.
// waves 0-7: loaders (plain global_load_dwordx4 -> regs -> ds_write).
// waves 8-9: compute (128 neurons, 1 per thread).
constexpr int NPB     = 128;                  // neurons per block
constexpr int C_STEPS = 16;                   // timesteps per buffer
constexpr int NBUF    = T_STEPS / C_STEPS;    // 64
constexpr int LWAVES  = 8;                    // loader waves
constexpr int FPW     = 3;                    // float4 loads per loader wave per buffer
constexpr size_t BUF_STRIDE = (size_t)C_STEPS * BN;   // floats between buffers

} // namespace

// One LIF step, byte-identical numerics to all passing rounds.
#define LIF_STEP(ec, ic, vc, tidx)                                         \
    do {                                                                   \
        float t      = (float)(tidx) * DT_F;                               \
        bool  active = (t - ls) >= REFRAC_F;                               \
        float totI   = ((ec) - A) + (ic);                                  \
        float Vn     = (V + (DT_F * (totI - GLEAK_F * V)) / CMEM_F) + (vc);\
        float An     = A * DECAY_F;                                        \
        float V1     = active ? Vn : V;                                    \
        float A1     = active ? An : A;                                    \
        bool  spike  = active && (V1 >= VTH_F);                            \
        V  = spike ? VRESET_F : V1;                                        \
        A  = spike ? (A1 + AINC_F) : A1;                                   \
        ls = spike ? t : ls;                                               \
        count += spike ? 1 : 0;                                            \
    } while (0)

__global__ __launch_bounds__(640, 1) void lif_sim_kernel(
    const float* __restrict__ ext,
    const float* __restrict__ inz,
    const float* __restrict__ vnz,
    float* __restrict__ rates)
{
    // double buffer: [slot][array][t][neuron] = 2 x 24 KB = 48 KB
    __shared__ float smem[2][3][C_STEPS][NPB];

    const int tid  = threadIdx.x;
    const int lane = tid & 63;
    const int w    = tid >> 6;          // 0..9
    const int n0   = blockIdx.x * NPB;

    if (w < LWAVES) {
        // ---------------- loader waves (8), pure TLP ----------------
        // flat float4 index within a buffer: e = i*512 + w*64 + lane
        // -> a = e>>9, tt = (e&511)>>5, n4 = e&31. Each wave-instr covers
        // 64 consecutive float4 = 1 KB (2 x 512B t-rows).
        const float* gp[FPW];
        float* d0[FPW];
        float* d1[FPW];
#pragma unroll
        for (int i = 0; i < FPW; ++i) {
            const int e  = i * 512 + w * 64 + lane;
            const int a  = e >> 9;
            const int ea = e & 511;
            const int tt = ea >> 5;
            const int n4 = (ea & 31) * 4;
            const float* ba = (a == 0) ? ext : ((a == 1) ? inz : vnz);
            gp[i] = ba + (size_t)tt * BN + (n0 + n4);
            d0[i] = &smem[0][a][tt][n4];
            d1[i] = &smem[1][a][tt][n4];
        }

        float4 ra[FPW], rb[FPW];

#define ISSUE(R)                                                           \
        do {                                                               \
            _Pragma("unroll")                                              \
            for (int i = 0; i < FPW; ++i) {                                \
                R[i] = *(const float4*)gp[i];                              \
                gp[i] += BUF_STRIDE;                                       \
            }                                                              \
        } while (0)

        // prologue: buffers 0 and 1 in flight (6 KB/wave outstanding)
        ISSUE(ra); ISSUE(rb);

        for (int j = 0; j < NBUF; j += 2) {
            // ---- buffer j (regs ra, slot 0) ----
            asm volatile("s_waitcnt vmcnt(3)" ::: "memory");   // rb still out
            __builtin_amdgcn_sched_barrier(0);
#pragma unroll
            for (int i = 0; i < FPW; ++i) *(float4*)d0[i] = ra[i];
            asm volatile("s_waitcnt lgkmcnt(0)" ::: "memory");
            if (j + 2 < NBUF) { ISSUE(ra); }
            __builtin_amdgcn_sched_barrier(0);
            __builtin_amdgcn_s_barrier();
            __builtin_amdgcn_sched_barrier(0);

            // ---- buffer j+1 (regs rb, slot 1) ----
            if (j + 1 < NBUF - 1) {
                asm volatile("s_waitcnt vmcnt(3)" ::: "memory");
            } else {
                asm volatile("s_waitcnt vmcnt(0)" ::: "memory");
            }
            __builtin_amdgcn_sched_barrier(0);
#pragma unroll
            for (int i = 0; i < FPW; ++i) *(float4*)d1[i] = rb[i];
            asm volatile("s_waitcnt lgkmcnt(0)" ::: "memory");
            if (j + 3 < NBUF) { ISSUE(rb); }
            __builtin_amdgcn_sched_barrier(0);
            __builtin_amdgcn_s_barrier();
            __builtin_amdgcn_sched_barrier(0);
        }
#undef ISSUE
    } else {
        // ---------------- compute waves (2): 1 neuron per thread ----------------
        const int tc = tid - LWAVES * 64;   // 0..127
        float V = 0.0f, A = 0.0f, ls = -1e9f;
        int count = 0;

        for (int k = 0; k < NBUF; ++k) {
            __builtin_amdgcn_s_barrier();
            __builtin_amdgcn_sched_barrier(0);
            const int s = k & 1;
#pragma unroll
            for (int c = 0; c < C_STEPS; ++c) {
                float ec = smem[s][0][c][tc];
                float ic = smem[s][1][c][tc];
                float vc = smem[s][2][c][tc];
                LIF_STEP(ec, ic, vc, k * C_STEPS + c);
            }
            __builtin_amdgcn_sched_barrier(0);   // keep reads inside the window
        }
        rates[n0 + tc] = (float)count * (1.0f / 1024.0f);
    }
}

// ---------------- readout: rates[16,2048] @ (Gn*0.1)[2048,512] ----------------
constexpr int KC   = 8;
constexpr int KCH  = NNEUR / KC;    // 256 k per chunk
constexpr int KSUB = 4;             // waves per block splitting the chunk
constexpr int KPT  = KCH / KSUB;    // 64 k per thread

__global__ __launch_bounds__(256) void readout_partial_kernel(
    const float* __restrict__ rates,
    const float* __restrict__ G,
    const float* __restrict__ cn,
    float* __restrict__ part)
{
    __shared__ float red[KSUB][64][BATCH + 1];

    const int tid = threadIdx.x;
    const int ml  = tid & 63;
    const int s   = tid >> 6;
    const int m   = blockIdx.x * 64 + ml;
    const int kc  = blockIdx.y;
    const int k0  = kc * KCH + s * KPT;

    float acc[BATCH];
#pragma unroll
    for (int b = 0; b < BATCH; ++b) acc[b] = 0.0f;

#pragma unroll 4
    for (int k = k0; k < k0 + KPT; ++k) {
        float g = G[(size_t)k * MCOLS + m];
        float c = cn[(size_t)k * MCOLS + m];
        float w = fmaxf(1e-8f, g * (1.0f + 0.1118f * c)) * 0.1f;  // Gn * READ_V
#pragma unroll
        for (int b = 0; b < BATCH; ++b) {
            acc[b] = fmaf(rates[b * NNEUR + k], w, acc[b]);
        }
    }

#pragma unroll
    for (int b = 0; b < BATCH; ++b) red[s][ml][b] = acc[b];
    __syncthreads();

    if (s == 0) {
#pragma unroll
        for (int b = 0; b < BATCH; ++b) {
            float v = ((red[0][ml][b] + red[1][ml][b]) + red[2][ml][b]) + red[3][ml][b];
            part[((size_t)kc * BATCH + b) * MCOLS + m] = v;
        }
    }
}

__global__ __launch_bounds__(256) void readout_reduce_kernel(
    const float* __restrict__ part,
    float* __restrict__ out)
{
    const int i = blockIdx.x * 256 + threadIdx.x;  // 0..8191 = b*512+m
    float s = 0.0f;
#pragma unroll
    for (int kc = 0; kc < KC; ++kc) {
        s += part[kc * (BATCH * MCOLS) + i];
    }
    out[i] = s;
}

extern "C" void kernel_launch(void* const* d_in, const int* in_sizes, int n_in,
                              void* d_out, int out_size, void* d_ws, size_t ws_size,
                              hipStream_t stream)
{
    const float* ext = (const float*)d_in[0];   // [T,B,N]
    const float* inz = (const float*)d_in[1];   // [T,B,N]
    const float* vnz = (const float*)d_in[2];   // [T,B,N]
    const float* G   = (const float*)d_in[3];   // [N,M]
    const float* cn  = (const float*)d_in[4];   // [N,M]
    float* out = (float*)d_out;                 // [B,M] = 8192

    float* rates = (float*)d_ws;                // 32768 floats
    float* part  = rates + BN;                  // 8*16*512 = 65536 floats

    lif_sim_kernel<<<BN / NPB, 640, 0, stream>>>(ext, inz, vnz, rates);
    readout_partial_kernel<<<dim3(MCOLS / 64, KC), 256, 0, stream>>>(rates, G, cn, part);
    readout_reduce_kernel<<<(BATCH * MCOLS) / 256, 256, 0, stream>>>(part, out);
}

// Round 10
// 106.550 us; speedup vs baseline: 1.5749x; 1.5749x over previous
//
#include <hip/hip_runtime.h>

namespace {

constexpr int T_STEPS = 1024;
constexpr int BATCH   = 16;
constexpr int NNEUR   = 2048;
constexpr int MCOLS   = 512;
constexpr int BN      = BATCH * NNEUR;   // 32768

constexpr double DT_D   = 1e-7;
constexpr double TAU_D  = 1e-4;

constexpr float DT_F     = 1e-7f;
constexpr float CMEM_F   = 1e-12f;
constexpr float GLEAK_F  = 1e-9f;
constexpr float VTH_F    = 0.7f;             // VTH * GAIN
constexpr float REFRAC_F = 1e-6f;
constexpr float AINC_F   = 5e-11f;
constexpr float DECAY_F  = (float)(1.0 - DT_D / TAU_D);   // 0.999f
constexpr float VRESET_F = 0.0f;

// Block-TLP design: 512 blocks x 256 threads (2 blocks per CU).
// wave 0: compute (64 neurons, 1/thread). waves 1-3: one loader wave per array.
// No inline asm, no cross-barrier register liveness: each loader iteration is
// load(8xfloat4) -> compiler-managed wait -> ds_write -> __syncthreads().
// Overlap comes from compute-vs-load concurrency inside the block plus the
// co-resident second block's staggered phases.
constexpr int NPB     = 64;                   // neurons per block
constexpr int C_STEPS = 32;                   // timesteps per buffer
constexpr int NBUF    = T_STEPS / C_STEPS;    // 32
constexpr int FPW     = 8;                    // float4 loads per loader wave per buffer

} // namespace

// One LIF step, byte-identical numerics to all passing rounds.
#define LIF_STEP(ec, ic, vc, tidx)                                         \
    do {                                                                   \
        float t      = (float)(tidx) * DT_F;                               \
        bool  active = (t - ls) >= REFRAC_F;                               \
        float totI   = ((ec) - A) + (ic);                                  \
        float Vn     = (V + (DT_F * (totI - GLEAK_F * V)) / CMEM_F) + (vc);\
        float An     = A * DECAY_F;                                        \
        float V1     = active ? Vn : V;                                    \
        float A1     = active ? An : A;                                    \
        bool  spike  = active && (V1 >= VTH_F);                            \
        V  = spike ? VRESET_F : V1;                                        \
        A  = spike ? (A1 + AINC_F) : A1;                                   \
        ls = spike ? t : ls;                                               \
        count += spike ? 1 : 0;                                            \
    } while (0)

__global__ __launch_bounds__(256, 2) void lif_sim_kernel(
    const float* __restrict__ ext,
    const float* __restrict__ inz,
    const float* __restrict__ vnz,
    float* __restrict__ rates)
{
    // double buffer: [slot][array][t][neuron] = 2*3*32*64*4 = 48 KB
    __shared__ float smem[2][3][C_STEPS][NPB];

    const int tid  = threadIdx.x;
    const int lane = tid & 63;
    const int w    = tid >> 6;          // 0..3
    const int n0   = blockIdx.x * NPB;

    if (w > 0) {
        // ---------------- loader wave for array a = w-1 ----------------
        const int a = w - 1;
        const float* ba = (a == 0) ? ext : ((a == 1) ? inz : vnz);
        const int r0  = lane >> 4;          // 0..3 (row within a 4-row chunk)
        const int col = (lane & 15) * 4;    // float col within the 64-neuron row
        const float* gbase = ba + n0 + col;

        for (int j = 0; j < NBUF; ++j) {
            float4 tmp[FPW];
#pragma unroll
            for (int i = 0; i < FPW; ++i)
                tmp[i] = *(const float4*)(gbase +
                         (size_t)(j * C_STEPS + i * 4 + r0) * BN);
#pragma unroll
            for (int i = 0; i < FPW; ++i)
                *(float4*)&smem[j & 1][a][i * 4 + r0][col] = tmp[i];
            __syncthreads();    // publish buffer j; rendezvous with compute
        }
    } else {
        // ---------------- compute wave: 1 neuron per thread ----------------
        float V = 0.0f, A = 0.0f, ls = -1e9f;
        int count = 0;

        for (int j = 0; j < NBUF; ++j) {
            __syncthreads();    // buffer j published; loaders start j+1 now
            const int s = j & 1;
#pragma unroll
            for (int c = 0; c < C_STEPS; ++c) {
                float ec = smem[s][0][c][lane];
                float ic = smem[s][1][c][lane];
                float vc = smem[s][2][c][lane];
                LIF_STEP(ec, ic, vc, j * C_STEPS + c);
            }
        }
        rates[n0 + lane] = (float)count * (1.0f / 1024.0f);
    }
}

// ---------------- readout: rates[16,2048] @ (Gn*0.1)[2048,512] ----------------
constexpr int KC   = 8;
constexpr int KCH  = NNEUR / KC;    // 256 k per chunk
constexpr int KSUB = 4;             // waves per block splitting the chunk
constexpr int KPT  = KCH / KSUB;    // 64 k per thread

__global__ __launch_bounds__(256) void readout_partial_kernel(
    const float* __restrict__ rates,
    const float* __restrict__ G,
    const float* __restrict__ cn,
    float* __restrict__ part)
{
    __shared__ float red[KSUB][64][BATCH + 1];

    const int tid = threadIdx.x;
    const int ml  = tid & 63;
    const int s   = tid >> 6;
    const int m   = blockIdx.x * 64 + ml;
    const int kc  = blockIdx.y;
    const int k0  = kc * KCH + s * KPT;

    float acc[BATCH];
#pragma unroll
    for (int b = 0; b < BATCH; ++b) acc[b] = 0.0f;

#pragma unroll 4
    for (int k = k0; k < k0 + KPT; ++k) {
        float g = G[(size_t)k * MCOLS + m];
        float c = cn[(size_t)k * MCOLS + m];
        float w = fmaxf(1e-8f, g * (1.0f + 0.1118f * c)) * 0.1f;  // Gn * READ_V
#pragma unroll
        for (int b = 0; b < BATCH; ++b) {
            acc[b] = fmaf(rates[b * NNEUR + k], w, acc[b]);
        }
    }

#pragma unroll
    for (int b = 0; b < BATCH; ++b) red[s][ml][b] = acc[b];
    __syncthreads();

    if (s == 0) {
#pragma unroll
        for (int b = 0; b < BATCH; ++b) {
            float v = ((red[0][ml][b] + red[1][ml][b]) + red[2][ml][b]) + red[3][ml][b];
            part[((size_t)kc * BATCH + b) * MCOLS + m] = v;
        }
    }
}

__global__ __launch_bounds__(256) void readout_reduce_kernel(
    const float* __restrict__ part,
    float* __restrict__ out)
{
    const int i = blockIdx.x * 256 + threadIdx.x;  // 0..8191 = b*512+m
    float s = 0.0f;
#pragma unroll
    for (int kc = 0; kc < KC; ++kc) {
        s += part[kc * (BATCH * MCOLS) + i];
    }
    out[i] = s;
}

extern "C" void kernel_launch(void* const* d_in, const int* in_sizes, int n_in,
                              void* d_out, int out_size, void* d_ws, size_t ws_size,
                              hipStream_t stream)
{
    const float* ext = (const float*)d_in[0];   // [T,B,N]
    const float* inz = (const float*)d_in[1];   // [T,B,N]
    const float* vnz = (const float*)d_in[2];   // [T,B,N]
    const float* G   = (const float*)d_in[3];   // [N,M]
    const float* cn  = (const float*)d_in[4];   // [N,M]
    float* out = (float*)d_out;                 // [B,M] = 8192

    float* rates = (float*)d_ws;                // 32768 floats
    float* part  = rates + BN;                  // 8*16*512 = 65536 floats

    lif_sim_kernel<<<BN / NPB, 256, 0, stream>>>(ext, inz, vnz, rates);
    readout_partial_kernel<<<dim3(MCOLS / 64, KC), 256, 0, stream>>>(rates, G, cn, part);
    readout_reduce_kernel<<<(BATCH * MCOLS) / 256, 256, 0, stream>>>(part, out);
}